// Round 2
// baseline (1887.068 us; speedup 1.0000x reference)
//
#include <hip/hip_runtime.h>
#include <stdint.h>

#define NODES   100000
#define NPAD    100096   // 782 * 128
#define DIM     512
#define NPAIR   2048
#define MROWS   4096     // 2048 l-rows + 2048 r-rows
#define NB      782      // NPAD / TN  (n-blocks)
#define GAMMA_F 3.0f
#define LAMB_F  20.0f
#define TAU_F   8.0f

#define TM 128
#define TN 128
#define BK 64

typedef __attribute__((ext_vector_type(8))) short          short8;
typedef __attribute__((ext_vector_type(8))) unsigned short ushort8;
typedef __attribute__((ext_vector_type(4))) float          f32x4;

// ---- helpers -------------------------------------------------------------

__device__ __forceinline__ unsigned short f2bf(float f) {
    unsigned u = __float_as_uint(f);
    u += 0x7FFFu + ((u >> 16) & 1u);   // RNE
    return (unsigned short)(u >> 16);
}

// async global->LDS, 16B per lane; lds dest = wave-uniform base + lane*16
__device__ __forceinline__ void gload_lds16(const void* g, void* l) {
    unsigned lofs = (unsigned)__builtin_amdgcn_readfirstlane((unsigned)(uintptr_t)l);
    auto lp = reinterpret_cast<__attribute__((address_space(3))) unsigned*>(lofs);
    auto gp = (const __attribute__((address_space(1))) unsigned*)g;
    __builtin_amdgcn_global_load_lds(gp, lp, 16, 0, 0);
}

// ---- prep kernels --------------------------------------------------------

// emb fp32 -> bf16 (zero-padded rows), and esq[j] = sum emb[j]^2
__global__ void convert_kernel(const float* __restrict__ emb,
                               unsigned short* __restrict__ Ebf,
                               float* __restrict__ esq) {
    const int row  = blockIdx.x * 4 + (threadIdx.x >> 6);
    const int lane = threadIdx.x & 63;
    float v[8];
    float ss = 0.f;
    if (row < NODES) {
        const float4* p = (const float4*)(emb + row * DIM + lane * 8);
        float4 a = p[0], b = p[1];
        v[0]=a.x; v[1]=a.y; v[2]=a.z; v[3]=a.w;
        v[4]=b.x; v[5]=b.y; v[6]=b.z; v[7]=b.w;
        #pragma unroll
        for (int i = 0; i < 8; ++i) ss += v[i] * v[i];
    } else {
        #pragma unroll
        for (int i = 0; i < 8; ++i) v[i] = 0.f;
    }
    ushort8 o;
    #pragma unroll
    for (int i = 0; i < 8; ++i) o[i] = f2bf(v[i]);
    *(ushort8*)(Ebf + row * DIM + lane * 8) = o;
    #pragma unroll
    for (int off = 1; off < 64; off <<= 1) ss += __shfl_xor(ss, off);
    if (lane == 0) esq[row] = ss;
}

// gather A rows (bf16) + c[m] = pos - |a|^2 + gamma
__global__ void gather_kernel(const int* __restrict__ pairs,
                              const float* __restrict__ emb,
                              unsigned short* __restrict__ Abf,
                              float* __restrict__ cvec) {
    const int p    = blockIdx.x;
    const int lane = threadIdx.x;
    const int li = pairs[2 * p], ri = pairs[2 * p + 1];
    const float4* pl = (const float4*)(emb + li * DIM + lane * 8);
    const float4* pr = (const float4*)(emb + ri * DIM + lane * 8);
    float4 a0 = pl[0], a1 = pl[1];
    float4 b0 = pr[0], b1 = pr[1];
    float la[8] = {a0.x,a0.y,a0.z,a0.w,a1.x,a1.y,a1.z,a1.w};
    float lb[8] = {b0.x,b0.y,b0.z,b0.w,b1.x,b1.y,b1.z,b1.w};
    float sa = 0.f, sb = 0.f, sd = 0.f;
    ushort8 oa, ob;
    #pragma unroll
    for (int i = 0; i < 8; ++i) {
        sa += la[i] * la[i];
        sb += lb[i] * lb[i];
        float d = la[i] - lb[i];
        sd += d * d;
        oa[i] = f2bf(la[i]);
        ob[i] = f2bf(lb[i]);
    }
    *(ushort8*)(Abf + p * DIM + lane * 8)            = oa;
    *(ushort8*)(Abf + (NPAIR + p) * DIM + lane * 8)  = ob;
    #pragma unroll
    for (int off = 1; off < 64; off <<= 1) {
        sa += __shfl_xor(sa, off);
        sb += __shfl_xor(sb, off);
        sd += __shfl_xor(sd, off);
    }
    if (lane == 0) {
        cvec[p]         = sd - sa + GAMMA_F;
        cvec[NPAIR + p] = sd - sb + GAMMA_F;
    }
}

// ---- the GEMM (+ fused epilogue), PASS=1 stat partials, PASS=2 exp partials
// No atomics anywhere: per-block partials to [nb][row] arrays (deterministic).

template <int PASS>
__launch_bounds__(256, 2)
__global__ void gemm_kernel(const unsigned short* __restrict__ Abf,
                            const unsigned short* __restrict__ Ebf,
                            const float* __restrict__ cvec,
                            const float* __restrict__ esq,
                            const int*   __restrict__ pairs,
                            float* __restrict__ psum,
                            float* __restrict__ pss,
                            float* __restrict__ pmax,
                            const float* __restrict__ alpha_v,
                            const float* __restrict__ xmax_v,
                            float* __restrict__ pexp) {
    __shared__ unsigned short ldsA[TM * BK];  // 16 KB
    __shared__ unsigned short ldsB[TN * BK];  // 16 KB
    __shared__ float red_s1[2][TM];           // epilogue combine scratch
    __shared__ float red_s2[2][TM];
    __shared__ float red_mx[2][TM];

    const int tid  = threadIdx.x;
    const int lane = tid & 63;
    const int wave = tid >> 6;
    const int wx = wave & 1;    // n-quadrant
    const int wy = wave >> 1;   // m-quadrant
    const int nb = blockIdx.x;
    const int n0 = nb * TN;
    const int m0 = blockIdx.y * TM;

    f32x4 zero4 = {0.f, 0.f, 0.f, 0.f};
    f32x4 acc[4][4];
    #pragma unroll
    for (int i = 0; i < 4; ++i)
        #pragma unroll
        for (int j = 0; j < 4; ++j) acc[i][j] = zero4;

    const int lrow   = lane >> 3;  // 0..7 row within 8-row issue
    const int lchunk = lane & 7;   // 0..7 16B-chunk slot within row
    const int r15 = lane & 15;
    const int q   = lane >> 4;

    for (int kt = 0; kt < DIM / BK; ++kt) {
        const int kb = kt * BK;
        #pragma unroll
        for (int j = 0; j < 4; ++j) {
            const int rbase = (wave * 4 + j) * 8;
            const int row   = rbase + lrow;
            const int gch   = lchunk ^ (row & 7);    // XOR swizzle (bank-conflict fix)
            gload_lds16(Abf + ((m0 + row) * DIM + kb + gch * 8), &ldsA[rbase * BK]);
            gload_lds16(Ebf + ((n0 + row) * DIM + kb + gch * 8), &ldsB[rbase * BK]);
        }
        __builtin_amdgcn_s_waitcnt(0);   // explicit drain insurance
        __syncthreads();
        #pragma unroll
        for (int h = 0; h < 2; ++h) {
            short8 af[4], bfr[4];
            #pragma unroll
            for (int mt = 0; mt < 4; ++mt) {
                int row = wy * 64 + mt * 16 + r15;
                int c   = (h * 4 + q) ^ (row & 7);
                af[mt] = *(const short8*)&ldsA[row * BK + c * 8];
            }
            #pragma unroll
            for (int nt = 0; nt < 4; ++nt) {
                int row = wx * 64 + nt * 16 + r15;
                int c   = (h * 4 + q) ^ (row & 7);
                bfr[nt] = *(const short8*)&ldsB[row * BK + c * 8];
            }
            #pragma unroll
            for (int mt = 0; mt < 4; ++mt)
                #pragma unroll
                for (int nt = 0; nt < 4; ++nt)
                    acc[mt][nt] = __builtin_amdgcn_mfma_f32_16x16x32_bf16(
                        af[mt], bfr[nt], acc[mt][nt], 0, 0, 0);
        }
        __syncthreads();
    }

    // epilogue: C/D layout col = lane&15 (n), row-in-16x16 = q*4 + reg (m)
    #pragma unroll
    for (int mt = 0; mt < 4; ++mt) {
        #pragma unroll
        for (int r = 0; r < 4; ++r) {
            const int rit = wy * 64 + mt * 16 + q * 4 + r;  // row in tile 0..127
            const int gm  = m0 + rit;
            const int p   = gm & (NPAIR - 1);
            const int li = pairs[2 * p], ri = pairs[2 * p + 1];
            const float cm = cvec[gm];
            if (PASS == 1) {
                float s1 = 0.f, s2 = 0.f, mx = -3.4e38f;
                #pragma unroll
                for (int nt = 0; nt < 4; ++nt) {
                    const int gn = n0 + wx * 64 + nt * 16 + r15;
                    if (gn < NODES) {
                        float xv = cm + 2.0f * acc[mt][nt][r] - esq[gn];
                        float msk = 1.0f - (float)(gn == li) - (float)(gn == ri);
                        xv *= msk;
                        s1 += xv; s2 += xv * xv; mx = fmaxf(mx, xv);
                    }
                }
                #pragma unroll
                for (int o = 1; o < 16; o <<= 1) {
                    s1 += __shfl_xor(s1, o);
                    s2 += __shfl_xor(s2, o);
                    mx  = fmaxf(mx, __shfl_xor(mx, o));
                }
                if (r15 == 0) {
                    red_s1[wx][rit] = s1;
                    red_s2[wx][rit] = s2;
                    red_mx[wx][rit] = mx;
                }
            } else {
                const float al = alpha_v[gm];
                const float xm = xmax_v[gm];
                float se = 0.f;
                #pragma unroll
                for (int nt = 0; nt < 4; ++nt) {
                    const int gn = n0 + wx * 64 + nt * 16 + r15;
                    if (gn < NODES) {
                        float xv = cm + 2.0f * acc[mt][nt][r] - esq[gn];
                        float msk = 1.0f - (float)(gn == li) - (float)(gn == ri);
                        xv *= msk;
                        se += __expf(al * (xv - xm));
                    }
                }
                #pragma unroll
                for (int o = 1; o < 16; o <<= 1) se += __shfl_xor(se, o);
                if (r15 == 0) red_s1[wx][rit] = se;
            }
        }
    }
    __syncthreads();
    if (tid < TM) {
        const int gm = m0 + tid;
        if (PASS == 1) {
            psum[(size_t)nb * MROWS + gm] = red_s1[0][tid] + red_s1[1][tid];
            pss [(size_t)nb * MROWS + gm] = red_s2[0][tid] + red_s2[1][tid];
            pmax[(size_t)nb * MROWS + gm] = fmaxf(red_mx[0][tid], red_mx[1][tid]);
        } else {
            pexp[(size_t)nb * MROWS + gm] = red_s1[0][tid] + red_s1[1][tid];
        }
    }
}

// ---- deterministic reductions -------------------------------------------

__global__ void reduce1_kernel(const float* __restrict__ psum,
                               const float* __restrict__ pss,
                               const float* __restrict__ pmax,
                               float* __restrict__ alpha_v,
                               float* __restrict__ xmax_v,
                               float* __restrict__ base_v) {
    const int row = blockIdx.x * 256 + threadIdx.x;
    if (row >= MROWS) return;
    double s = 0.0, ss = 0.0;
    float mx = -3.4e38f;
    for (int nb = 0; nb < NB; ++nb) {
        s  += (double)psum[(size_t)nb * MROWS + row];
        ss += (double)pss [(size_t)nb * MROWS + row];
        mx  = fmaxf(mx, pmax[(size_t)nb * MROWS + row]);
    }
    const double invN = 1.0 / (double)NODES;
    double mu  = s * invN;
    double var = ss * invN - mu * mu;
    double sd  = sqrt(fmax(var, 1e-30));
    alpha_v[row] = (float)((double)LAMB_F / sd);
    xmax_v[row]  = mx;
    base_v[row]  = (float)((double)TAU_F + ((double)LAMB_F / sd) * ((double)mx - mu));
}

__global__ void reduce2_kernel(const float* __restrict__ pexp,
                               const float* __restrict__ base_v,
                               float* __restrict__ loss_v) {
    const int row = blockIdx.x * 256 + threadIdx.x;
    if (row >= MROWS) return;
    double se = 0.0;
    for (int nb = 0; nb < NB; ++nb)
        se += (double)pexp[(size_t)nb * MROWS + row];
    loss_v[row] = (float)((double)base_v[row] + log(se));
}

__global__ void final_kernel(const float* __restrict__ loss_v,
                             float* __restrict__ out) {
    __shared__ double wpart[4];
    int t = threadIdx.x;
    double s = 0.0;
    for (int i = t; i < MROWS; i += 256)
        s += (double)loss_v[i];
    #pragma unroll
    for (int off = 1; off < 64; off <<= 1) s += __shfl_xor(s, off);
    if ((t & 63) == 0) wpart[t >> 6] = s;
    __syncthreads();
    if (t == 0) out[0] = (float)((wpart[0] + wpart[1] + wpart[2] + wpart[3]) / (double)NPAIR);
}

// ---- host ----------------------------------------------------------------

extern "C" void kernel_launch(void* const* d_in, const int* in_sizes, int n_in,
                              void* d_out, int out_size, void* d_ws, size_t ws_size,
                              hipStream_t stream) {
    const int*   pairs = (const int*)d_in[0];
    const float* emb   = (const float*)d_in[1];
    float* out = (float*)d_out;

    char* ws = (char*)d_ws;
    size_t off = 0;
    auto alloc = [&](size_t bytes) -> void* {
        void* p = ws + off;
        off += (bytes + 255) & ~(size_t)255;
        return p;
    };
    unsigned short* Ebf = (unsigned short*)alloc((size_t)NPAD * DIM * 2);
    unsigned short* Abf = (unsigned short*)alloc((size_t)MROWS * DIM * 2);
    float* cvec    = (float*)alloc((size_t)MROWS * 4);
    float* esq     = (float*)alloc((size_t)NPAD * 4);
    float* psum    = (float*)alloc((size_t)NB * MROWS * 4);
    float* pss     = (float*)alloc((size_t)NB * MROWS * 4);
    float* pmax    = (float*)alloc((size_t)NB * MROWS * 4);
    float* alpha_v = (float*)alloc((size_t)MROWS * 4);
    float* xmax_v  = (float*)alloc((size_t)MROWS * 4);
    float* base_v  = (float*)alloc((size_t)MROWS * 4);
    float* loss_v  = (float*)alloc((size_t)MROWS * 4);
    float* pexp    = psum;   // alias: psum dead after reduce1, pexp born in pass 2
    if (off > ws_size) return;  // workspace too small — fail cleanly (visible as absmax=|ref|)

    convert_kernel<<<NPAD / 4, 256, 0, stream>>>(emb, Ebf, esq);
    gather_kernel<<<NPAIR, 64, 0, stream>>>(pairs, emb, Abf, cvec);

    dim3 grid(NB, MROWS / TM);
    gemm_kernel<1><<<grid, 256, 0, stream>>>(Abf, Ebf, cvec, esq, pairs,
                                             psum, pss, pmax,
                                             alpha_v, xmax_v, pexp);
    reduce1_kernel<<<MROWS / 256, 256, 0, stream>>>(psum, pss, pmax,
                                                    alpha_v, xmax_v, base_v);
    gemm_kernel<2><<<grid, 256, 0, stream>>>(Abf, Ebf, cvec, esq, pairs,
                                             psum, pss, pmax,
                                             alpha_v, xmax_v, pexp);
    reduce2_kernel<<<MROWS / 256, 256, 0, stream>>>(pexp, base_v, loss_v);
    final_kernel<<<1, 256, 0, stream>>>(loss_v, out);
}

// Round 3
// 1496.630 us; speedup vs baseline: 1.2609x; 1.2609x over previous
//
#include <hip/hip_runtime.h>
#include <stdint.h>

#define NODES   100000
#define NPAD    100096   // 782 * 128
#define DIM     512
#define NPAIR   2048
#define MROWS   4096     // 2048 l-rows + 2048 r-rows
#define NB      782      // NPAD / TN
#define MPAGES  32       // MROWS / 128
#define GAMMA_F 3.0f
#define LAMB_F  20.0f
#define TAU_F   8.0f

#define TM 128
#define TN 128
#define BK 64

typedef __attribute__((ext_vector_type(8))) short          short8;
typedef __attribute__((ext_vector_type(8))) unsigned short ushort8;
typedef __attribute__((ext_vector_type(4))) float          f32x4;

// ---- helpers -------------------------------------------------------------

__device__ __forceinline__ unsigned short f2bf(float f) {
    unsigned u = __float_as_uint(f);
    u += 0x7FFFu + ((u >> 16) & 1u);   // RNE
    return (unsigned short)(u >> 16);
}
__device__ __forceinline__ float bf2f(unsigned short h) {
    return __uint_as_float(((unsigned)h) << 16);
}

// async global->LDS, 16B per lane; lds dest = wave-uniform base + lane*16
__device__ __forceinline__ void gload_lds16(const void* g, void* l) {
    unsigned lofs = (unsigned)__builtin_amdgcn_readfirstlane((unsigned)(uintptr_t)l);
    auto lp = reinterpret_cast<__attribute__((address_space(3))) unsigned*>(lofs);
    auto gp = (const __attribute__((address_space(1))) unsigned*)g;
    __builtin_amdgcn_global_load_lds(gp, lp, 16, 0, 0);
}

// ---- prep kernels --------------------------------------------------------

// emb fp32 -> bf16 (zero-padded rows), and esq[j] = sum emb[j]^2 (fp32 exact)
__global__ void convert_kernel(const float* __restrict__ emb,
                               unsigned short* __restrict__ Ebf,
                               float* __restrict__ esq) {
    const int row  = blockIdx.x * 4 + (threadIdx.x >> 6);
    const int lane = threadIdx.x & 63;
    float v[8];
    float ss = 0.f;
    if (row < NODES) {
        const float4* p = (const float4*)(emb + (size_t)row * DIM + lane * 8);
        float4 a = p[0], b = p[1];
        v[0]=a.x; v[1]=a.y; v[2]=a.z; v[3]=a.w;
        v[4]=b.x; v[5]=b.y; v[6]=b.z; v[7]=b.w;
        #pragma unroll
        for (int i = 0; i < 8; ++i) ss += v[i] * v[i];
    } else {
        #pragma unroll
        for (int i = 0; i < 8; ++i) v[i] = 0.f;
    }
    ushort8 o;
    #pragma unroll
    for (int i = 0; i < 8; ++i) o[i] = f2bf(v[i]);
    *(ushort8*)(Ebf + (size_t)row * DIM + lane * 8) = o;
    #pragma unroll
    for (int off = 1; off < 64; off <<= 1) ss += __shfl_xor(ss, off);
    if (lane == 0) esq[row] = ss;
}

// per-block partial S = sum_j e_j (bf16-rounded, to match GEMM), T = sum esq_j*e_j,
// E1 = sum esq, E2 = sum esq^2.  256 blocks * 391 rows = 100096 rows.
__global__ void stats_part_kernel(const unsigned short* __restrict__ Ebf,
                                  const float* __restrict__ esq,
                                  float* __restrict__ Spart,
                                  float* __restrict__ Tpart,
                                  float* __restrict__ E1part,
                                  float* __restrict__ E2part) {
    __shared__ float lred[8];
    const int b = blockIdx.x, t = threadIdx.x;
    const int lane = t & 63, wave = t >> 6;
    const int r0 = b * 391;
    float s0 = 0.f, s1 = 0.f, t0 = 0.f, t1 = 0.f;
    for (int i = 0; i < 391; ++i) {
        const int row = r0 + i;
        unsigned pk = *(const unsigned*)(Ebf + (size_t)row * DIM + 2 * t);
        float eq = esq[row];
        float a = bf2f((unsigned short)(pk & 0xffffu));
        float c = bf2f((unsigned short)(pk >> 16));
        s0 += a; s1 += c; t0 += eq * a; t1 += eq * c;
    }
    Spart[b * DIM + 2 * t]     = s0;
    Spart[b * DIM + 2 * t + 1] = s1;
    Tpart[b * DIM + 2 * t]     = t0;
    Tpart[b * DIM + 2 * t + 1] = t1;
    // E1/E2: thread t covers rows r0+t and r0+t+256 (if in range)
    float e1 = 0.f, e2 = 0.f;
    {
        float q = esq[r0 + t];          e1 += q;  e2 += q * q;
        if (t + 256 < 391) { float q2 = esq[r0 + t + 256]; e1 += q2; e2 += q2 * q2; }
    }
    #pragma unroll
    for (int off = 1; off < 64; off <<= 1) {
        e1 += __shfl_xor(e1, off);
        e2 += __shfl_xor(e2, off);
    }
    if (lane == 0) { lred[wave] = e1; lred[4 + wave] = e2; }
    __syncthreads();
    if (t == 0) {
        E1part[b] = lred[0] + lred[1] + lred[2] + lred[3];
        E2part[b] = lred[4] + lred[5] + lred[6] + lred[7];
    }
}

__global__ void stats_merge_kernel(const float* __restrict__ Spart,
                                   const float* __restrict__ Tpart,
                                   const float* __restrict__ E1part,
                                   const float* __restrict__ E2part,
                                   float* __restrict__ Svec,
                                   float* __restrict__ Tvec,
                                   double* __restrict__ E12) {
    const int t = threadIdx.x;   // 512 threads
    float s = 0.f, tt = 0.f;
    for (int b = 0; b < 256; ++b) {
        s  += Spart[b * DIM + t];
        tt += Tpart[b * DIM + t];
    }
    Svec[t] = s; Tvec[t] = tt;
    if (t < 2) {
        const float* p = (t == 0) ? E1part : E2part;
        double acc = 0.0;
        for (int b = 0; b < 256; ++b) acc += (double)p[b];
        E12[t] = acc;
    }
}

// gather A rows (bf16) + c[m] = pos - |a|^2 + gamma ; posv[p] = pos
__global__ void gather_kernel(const int* __restrict__ pairs,
                              const float* __restrict__ emb,
                              unsigned short* __restrict__ Abf,
                              float* __restrict__ cvec,
                              float* __restrict__ posv) {
    const int p    = blockIdx.x;
    const int lane = threadIdx.x;
    const int li = pairs[2 * p], ri = pairs[2 * p + 1];
    const float4* pl = (const float4*)(emb + (size_t)li * DIM + lane * 8);
    const float4* pr = (const float4*)(emb + (size_t)ri * DIM + lane * 8);
    float4 a0 = pl[0], a1 = pl[1];
    float4 b0 = pr[0], b1 = pr[1];
    float la[8] = {a0.x,a0.y,a0.z,a0.w,a1.x,a1.y,a1.z,a1.w};
    float lb[8] = {b0.x,b0.y,b0.z,b0.w,b1.x,b1.y,b1.z,b1.w};
    float sa = 0.f, sb = 0.f, sd = 0.f;
    ushort8 oa, ob;
    #pragma unroll
    for (int i = 0; i < 8; ++i) {
        sa += la[i] * la[i];
        sb += lb[i] * lb[i];
        float d = la[i] - lb[i];
        sd += d * d;
        oa[i] = f2bf(la[i]);
        ob[i] = f2bf(lb[i]);
    }
    *(ushort8*)(Abf + (size_t)p * DIM + lane * 8)            = oa;
    *(ushort8*)(Abf + (size_t)(NPAIR + p) * DIM + lane * 8)  = ob;
    #pragma unroll
    for (int off = 1; off < 64; off <<= 1) {
        sa += __shfl_xor(sa, off);
        sb += __shfl_xor(sb, off);
        sd += __shfl_xor(sd, off);
    }
    if (lane == 0) {
        cvec[p]         = sd - sa + GAMMA_F;
        cvec[NPAIR + p] = sd - sb + GAMMA_F;
        posv[p]         = sd;
    }
}

// ---- Gram GEMM: Gpart[bz] += E^T E over the block's j-chunks -------------
// A[m=d1][k=j] = Ebf[j][d1] (transposed LDS reads via ds_read_u16)

__launch_bounds__(256, 2)
__global__ void gram_kernel(const unsigned short* __restrict__ Ebf,
                            float* __restrict__ Gpart) {
    __shared__ unsigned short ldsA[64 * 128];  // [j][d1] 16 KB
    __shared__ unsigned short ldsB[64 * 128];  // [j][d2] 16 KB
    const int tid  = threadIdx.x;
    const int lane = tid & 63;
    const int wave = tid >> 6;
    const int wx = wave & 1, wy = wave >> 1;
    const int d1base = blockIdx.y * 128;
    const int d2base = blockIdx.x * 128;
    const int bz = blockIdx.z;
    const int r15 = lane & 15, q = lane >> 4;

    f32x4 zero4 = {0.f, 0.f, 0.f, 0.f};
    f32x4 acc[4][4];
    #pragma unroll
    for (int i = 0; i < 4; ++i)
        #pragma unroll
        for (int j = 0; j < 4; ++j) acc[i][j] = zero4;

    for (int jc = bz; jc < NPAD / 64; jc += 32) {
        const int j0 = jc * 64;
        #pragma unroll
        for (int ii = 0; ii < 4; ++ii) {
            const int iss = wave * 4 + ii;           // 0..15
            const int row = iss * 4 + (lane >> 4);   // j row within 64
            gload_lds16(Ebf + (size_t)(j0 + row) * DIM + d1base + (lane & 15) * 8,
                        &ldsA[iss * 4 * 128]);
            gload_lds16(Ebf + (size_t)(j0 + row) * DIM + d2base + (lane & 15) * 8,
                        &ldsB[iss * 4 * 128]);
        }
        __builtin_amdgcn_s_waitcnt(0);
        __syncthreads();
        #pragma unroll
        for (int h = 0; h < 2; ++h) {
            short8 af[4], bfv[4];
            #pragma unroll
            for (int mt = 0; mt < 4; ++mt) {
                const int m = wy * 64 + mt * 16 + r15;
                #pragma unroll
                for (int i = 0; i < 8; ++i)
                    af[mt][i] = (short)ldsA[(h * 32 + q * 8 + i) * 128 + m];
            }
            #pragma unroll
            for (int nt = 0; nt < 4; ++nt) {
                const int n = wx * 64 + nt * 16 + r15;
                #pragma unroll
                for (int i = 0; i < 8; ++i)
                    bfv[nt][i] = (short)ldsB[(h * 32 + q * 8 + i) * 128 + n];
            }
            #pragma unroll
            for (int mt = 0; mt < 4; ++mt)
                #pragma unroll
                for (int nt = 0; nt < 4; ++nt)
                    acc[mt][nt] = __builtin_amdgcn_mfma_f32_16x16x32_bf16(
                        af[mt], bfv[nt], acc[mt][nt], 0, 0, 0);
        }
        __syncthreads();
    }
    float* gp = Gpart + (size_t)bz * 512 * 512;
    #pragma unroll
    for (int mt = 0; mt < 4; ++mt)
        #pragma unroll
        for (int r = 0; r < 4; ++r) {
            const int d1 = d1base + wy * 64 + mt * 16 + q * 4 + r;
            #pragma unroll
            for (int nt = 0; nt < 4; ++nt) {
                const int d2 = d2base + wx * 64 + nt * 16 + r15;
                gp[d1 * 512 + d2] = acc[mt][nt][r];
            }
        }
}

__global__ void gram_merge_kernel(const float* __restrict__ Gpart,
                                  float* __restrict__ G) {
    const int idx = blockIdx.x * 256 + threadIdx.x;   // 1024 blocks
    float s = 0.f;
    for (int b = 0; b < 32; ++b) s += Gpart[(size_t)b * 512 * 512 + idx];
    G[idx] = s;
}

// ---- per-row stats: q = u^T G u, dS = u.S, dT = u.T -> alpha, base -------
// 8 rows per block, 512 blocks.

__launch_bounds__(256)
__global__ void gu_kernel(const unsigned short* __restrict__ Abf,
                          const float* __restrict__ G,
                          const float* __restrict__ Svec,
                          const float* __restrict__ Tvec,
                          const double* __restrict__ E12,
                          const float* __restrict__ cvec,
                          const float* __restrict__ posv,
                          const int* __restrict__ pairs,
                          float* __restrict__ alpha_v,
                          float* __restrict__ base_v) {
    __shared__ float u[8][512];      // 16 KB
    __shared__ float red[8][3][4];
    const int t = threadIdx.x;
    const int lane = t & 63, wave = t >> 6;
    const int r0 = blockIdx.x * 8;
    #pragma unroll
    for (int p = 0; p < 8; ++p) {
        unsigned pk = *(const unsigned*)(Abf + (size_t)(r0 + p) * DIM + 2 * t);
        u[p][2 * t]     = bf2f((unsigned short)(pk & 0xffffu));
        u[p][2 * t + 1] = bf2f((unsigned short)(pk >> 16));
    }
    __syncthreads();
    float acc0[8], acc1[8];
    #pragma unroll
    for (int p = 0; p < 8; ++p) { acc0[p] = 0.f; acc1[p] = 0.f; }
    for (int d1 = 0; d1 < 512; ++d1) {
        const float2 g = *(const float2*)(G + d1 * 512 + 2 * t);
        #pragma unroll
        for (int p = 0; p < 8; ++p) {
            const float up = u[p][d1];
            acc0[p] += up * g.x;
            acc1[p] += up * g.y;
        }
    }
    const float sv0 = Svec[2 * t], sv1 = Svec[2 * t + 1];
    const float tv0 = Tvec[2 * t], tv1 = Tvec[2 * t + 1];
    #pragma unroll
    for (int p = 0; p < 8; ++p) {
        const float u0 = u[p][2 * t], u1 = u[p][2 * t + 1];
        float pdS = u0 * sv0 + u1 * sv1;
        float pdT = u0 * tv0 + u1 * tv1;
        float pq  = u0 * acc0[p] + u1 * acc1[p];
        #pragma unroll
        for (int off = 1; off < 64; off <<= 1) {
            pdS += __shfl_xor(pdS, off);
            pdT += __shfl_xor(pdT, off);
            pq  += __shfl_xor(pq,  off);
        }
        if (lane == 0) {
            red[p][0][wave] = pdS;
            red[p][1][wave] = pdT;
            red[p][2][wave] = pq;
        }
    }
    __syncthreads();
    if (t < 8) {
        const int p = t;
        const double dS = (double)red[p][0][0] + red[p][0][1] + red[p][0][2] + red[p][0][3];
        const double dT = (double)red[p][1][0] + red[p][1][1] + red[p][1][2] + red[p][1][3];
        const double qq = (double)red[p][2][0] + red[p][2][1] + red[p][2][2] + red[p][2][3];
        const int row = r0 + p;
        const int pp  = row & (NPAIR - 1);
        const double c  = (double)cvec[row];
        const double E1 = E12[0], E2 = E12[1];
        const double N  = (double)NODES;
        double Sx  = N * c + 2.0 * dS - E1;
        double Sxx = (N * c * c - 2.0 * c * E1 + E2) + 4.0 * (c * dS - dT) + 4.0 * qq;
        const int li = pairs[2 * pp], ri = pairs[2 * pp + 1];
        const double pos = (double)posv[pp];
        if (li != ri) {
            const double x1 = pos + (double)GAMMA_F, x2 = (double)GAMMA_F;
            Sx  -= x1 + x2;
            Sxx -= x1 * x1 + x2 * x2;
        } else {
            Sx -= 2.0 * (double)GAMMA_F;   // value flips sign; square unchanged
        }
        const double mu  = Sx / N;
        const double var = Sxx / N - mu * mu;
        const double sd  = sqrt(fmax(var, 1e-30));
        const double al  = (double)LAMB_F / sd;
        alpha_v[row] = (float)al;
        base_v[row]  = (float)((double)TAU_F - al * mu);
    }
}

// ---- the big GEMM (single pass) + online-LSE partial epilogue ------------

__launch_bounds__(256, 2)
__global__ void gemm_kernel(const unsigned short* __restrict__ Abf,
                            const unsigned short* __restrict__ Ebf,
                            const float* __restrict__ cvec,
                            const float* __restrict__ esq,
                            const int*   __restrict__ pairs,
                            const float* __restrict__ alpha_v,
                            float* __restrict__ pmax,
                            float* __restrict__ psum) {
    __shared__ unsigned short ldsA[TM * BK];  // 16 KB
    __shared__ unsigned short ldsB[TN * BK];  // 16 KB
    __shared__ float red_m[2][TM];
    __shared__ float red_s[2][TM];

    const int tid  = threadIdx.x;
    const int lane = tid & 63;
    const int wave = tid >> 6;
    const int wx = wave & 1;
    const int wy = wave >> 1;
    const int nb = blockIdx.x;
    const int n0 = nb * TN;
    const int m0 = blockIdx.y * TM;

    f32x4 zero4 = {0.f, 0.f, 0.f, 0.f};
    f32x4 acc[4][4];
    #pragma unroll
    for (int i = 0; i < 4; ++i)
        #pragma unroll
        for (int j = 0; j < 4; ++j) acc[i][j] = zero4;

    const int lrow   = lane >> 3;
    const int lchunk = lane & 7;
    const int r15 = lane & 15;
    const int q   = lane >> 4;

    for (int kt = 0; kt < DIM / BK; ++kt) {
        const int kb = kt * BK;
        #pragma unroll
        for (int j = 0; j < 4; ++j) {
            const int rbase = (wave * 4 + j) * 8;
            const int row   = rbase + lrow;
            const int gch   = lchunk ^ (row & 7);
            gload_lds16(Abf + ((size_t)(m0 + row) * DIM + kb + gch * 8), &ldsA[rbase * BK]);
            gload_lds16(Ebf + ((size_t)(n0 + row) * DIM + kb + gch * 8), &ldsB[rbase * BK]);
        }
        __builtin_amdgcn_s_waitcnt(0);
        __syncthreads();
        #pragma unroll
        for (int h = 0; h < 2; ++h) {
            short8 af[4], bfr[4];
            #pragma unroll
            for (int mt = 0; mt < 4; ++mt) {
                int row = wy * 64 + mt * 16 + r15;
                int c   = (h * 4 + q) ^ (row & 7);
                af[mt] = *(const short8*)&ldsA[row * BK + c * 8];
            }
            #pragma unroll
            for (int nt = 0; nt < 4; ++nt) {
                int row = wx * 64 + nt * 16 + r15;
                int c   = (h * 4 + q) ^ (row & 7);
                bfr[nt] = *(const short8*)&ldsB[row * BK + c * 8];
            }
            #pragma unroll
            for (int mt = 0; mt < 4; ++mt)
                #pragma unroll
                for (int nt = 0; nt < 4; ++nt)
                    acc[mt][nt] = __builtin_amdgcn_mfma_f32_16x16x32_bf16(
                        af[mt], bfr[nt], acc[mt][nt], 0, 0, 0);
        }
        __syncthreads();
    }

    // epilogue: online-LSE partials. C/D: col = lane&15 (n), row = q*4+reg (m)
    #pragma unroll
    for (int mt = 0; mt < 4; ++mt) {
        #pragma unroll
        for (int r = 0; r < 4; ++r) {
            const int rit = wy * 64 + mt * 16 + q * 4 + r;
            const int gm  = m0 + rit;
            const int p   = gm & (NPAIR - 1);
            const int li = pairs[2 * p], ri = pairs[2 * p + 1];
            const float cm = cvec[gm];
            const float al = alpha_v[gm];
            float xv[4];
            float mx = -3.0e38f;
            #pragma unroll
            for (int nt = 0; nt < 4; ++nt) {
                const int gn = n0 + wx * 64 + nt * 16 + r15;
                float v;
                if (gn < NODES) {
                    v = cm + 2.0f * acc[mt][nt][r] - esq[gn];
                    float msk = 1.0f - (float)(gn == li) - (float)(gn == ri);
                    v *= msk;
                } else {
                    v = -3.0e38f;
                }
                xv[nt] = v;
                mx = fmaxf(mx, v);
            }
            #pragma unroll
            for (int o = 1; o < 16; o <<= 1) mx = fmaxf(mx, __shfl_xor(mx, o));
            float se = 0.f;
            #pragma unroll
            for (int nt = 0; nt < 4; ++nt) se += __expf(al * (xv[nt] - mx));
            #pragma unroll
            for (int o = 1; o < 16; o <<= 1) se += __shfl_xor(se, o);
            if (r15 == 0) { red_m[wx][rit] = mx; red_s[wx][rit] = se; }
        }
    }
    __syncthreads();
    if (tid < TM) {
        const float al = alpha_v[m0 + tid];
        const float ma = red_m[0][tid], mb = red_m[1][tid];
        const float M  = fmaxf(ma, mb);
        const float s  = red_s[0][tid] * __expf(al * (ma - M))
                       + red_s[1][tid] * __expf(al * (mb - M));
        const size_t o = (size_t)blockIdx.y * (NB * TM) + (size_t)nb * TM + tid;
        pmax[o] = M;
        psum[o] = s;
    }
}

// ---- merge partials per row into loss ------------------------------------

__global__ void lse_merge_kernel(const float* __restrict__ pmax,
                                 const float* __restrict__ psum,
                                 const float* __restrict__ alpha_v,
                                 const float* __restrict__ base_v,
                                 float* __restrict__ loss_v) {
    const int page = blockIdx.x;        // 32
    const int t    = threadIdx.x;       // 128
    const int row  = page * 128 + t;
    const float al = alpha_v[row];
    const float* pm = pmax + (size_t)page * NB * 128 + t;
    const float* ps = psum + (size_t)page * NB * 128 + t;
    float M = -3.4e38f, S = 0.f;
    for (int nb = 0; nb < NB; ++nb) {
        const float m = pm[(size_t)nb * 128];
        const float s = ps[(size_t)nb * 128];
        if (m > M) { S = S * __expf(al * (M - m)) + s; M = m; }
        else       { S += s * __expf(al * (m - M)); }
    }
    loss_v[row] = base_v[row] + al * M + logf(S);
}

__global__ void final_kernel(const float* __restrict__ loss_v,
                             float* __restrict__ out) {
    __shared__ double wpart[4];
    int t = threadIdx.x;
    double s = 0.0;
    for (int i = t; i < MROWS; i += 256)
        s += (double)loss_v[i];
    #pragma unroll
    for (int off = 1; off < 64; off <<= 1) s += __shfl_xor(s, off);
    if ((t & 63) == 0) wpart[t >> 6] = s;
    __syncthreads();
    if (t == 0) out[0] = (float)((wpart[0] + wpart[1] + wpart[2] + wpart[3]) / (double)NPAIR);
}

// ---- host ----------------------------------------------------------------

extern "C" void kernel_launch(void* const* d_in, const int* in_sizes, int n_in,
                              void* d_out, int out_size, void* d_ws, size_t ws_size,
                              hipStream_t stream) {
    const int*   pairs = (const int*)d_in[0];
    const float* emb   = (const float*)d_in[1];
    float* out = (float*)d_out;

    char* ws = (char*)d_ws;
    size_t off = 0;
    auto alloc = [&](size_t bytes) -> void* {
        void* p = ws + off;
        off += (bytes + 255) & ~(size_t)255;
        return p;
    };
    unsigned short* Ebf = (unsigned short*)alloc((size_t)NPAD * DIM * 2);
    unsigned short* Abf = (unsigned short*)alloc((size_t)MROWS * DIM * 2);
    float*  esq     = (float*)alloc((size_t)NPAD * 4);
    float*  cvec    = (float*)alloc((size_t)MROWS * 4);
    float*  posv    = (float*)alloc((size_t)NPAIR * 4);
    float*  Spart   = (float*)alloc((size_t)256 * DIM * 4);
    float*  Tpart   = (float*)alloc((size_t)256 * DIM * 4);
    float*  E1part  = (float*)alloc((size_t)256 * 4);
    float*  E2part  = (float*)alloc((size_t)256 * 4);
    float*  Svec    = (float*)alloc((size_t)DIM * 4);
    float*  Tvec    = (float*)alloc((size_t)DIM * 4);
    double* E12     = (double*)alloc(2 * sizeof(double));
    float*  G       = (float*)alloc((size_t)512 * 512 * 4);
    float*  alpha_v = (float*)alloc((size_t)MROWS * 4);
    float*  base_v  = (float*)alloc((size_t)MROWS * 4);
    float*  loss_v  = (float*)alloc((size_t)MROWS * 4);
    // union region: Gram partials (32 MB) first, then LSE partials (25.6 MB)
    const size_t union_bytes_g = (size_t)32 * 512 * 512 * 4;
    const size_t union_bytes_p = (size_t)2 * MPAGES * NB * 128 * 4;
    char* uni = (char*)alloc(union_bytes_g > union_bytes_p ? union_bytes_g : union_bytes_p);
    float* Gpart = (float*)uni;
    float* pmax  = (float*)uni;
    float* psum  = (float*)(uni + (size_t)MPAGES * NB * 128 * 4);
    if (off > ws_size) return;  // workspace too small — fail visibly

    convert_kernel<<<NPAD / 4, 256, 0, stream>>>(emb, Ebf, esq);
    stats_part_kernel<<<256, 256, 0, stream>>>(Ebf, esq, Spart, Tpart, E1part, E2part);
    stats_merge_kernel<<<1, 512, 0, stream>>>(Spart, Tpart, E1part, E2part, Svec, Tvec, E12);
    gather_kernel<<<NPAIR, 64, 0, stream>>>(pairs, emb, Abf, cvec, posv);

    gram_kernel<<<dim3(4, 4, 32), 256, 0, stream>>>(Ebf, Gpart);
    gram_merge_kernel<<<1024, 256, 0, stream>>>(Gpart, G);
    gu_kernel<<<MROWS / 8, 256, 0, stream>>>(Abf, G, Svec, Tvec, E12,
                                             cvec, posv, pairs, alpha_v, base_v);

    gemm_kernel<<<dim3(NB, MPAGES), 256, 0, stream>>>(Abf, Ebf, cvec, esq, pairs,
                                                      alpha_v, pmax, psum);
    lse_merge_kernel<<<MPAGES, 128, 0, stream>>>(pmax, psum, alpha_v, base_v, loss_v);
    final_kernel<<<1, 256, 0, stream>>>(loss_v, out);
}

// Round 4
// 1100.130 us; speedup vs baseline: 1.7153x; 1.3604x over previous
//
#include <hip/hip_runtime.h>
#include <stdint.h>

#define NODES   100000
#define NPAD    100096   // 782 * 128
#define DIM     512
#define NPAIR   2048
#define MROWS   4096     // 2048 l-rows + 2048 r-rows
#define NB      782      // NPAD / TN
#define MPAGES  32       // MROWS / 128
#define GAMMA_F 3.0f
#define LAMB_F  20.0f
#define TAU_F   8.0f
#define SHIFT_F 140.0f   // LAMB * 7 (7-sigma LSE shift; see derivation in journal)

#define TM 128
#define TN 128
#define BK 64

typedef __attribute__((ext_vector_type(8))) short          short8;
typedef __attribute__((ext_vector_type(8))) unsigned short ushort8;
typedef __attribute__((ext_vector_type(4))) float          f32x4;

// ---- helpers -------------------------------------------------------------

__device__ __forceinline__ unsigned short f2bf(float f) {
    unsigned u = __float_as_uint(f);
    u += 0x7FFFu + ((u >> 16) & 1u);   // RNE
    return (unsigned short)(u >> 16);
}
__device__ __forceinline__ float bf2f(unsigned short h) {
    return __uint_as_float(((unsigned)h) << 16);
}

// async global->LDS, 16B per lane; lds dest = wave-uniform base + lane*16
__device__ __forceinline__ void gload_lds16(const void* g, void* l) {
    unsigned lofs = (unsigned)__builtin_amdgcn_readfirstlane((unsigned)(uintptr_t)l);
    auto lp = reinterpret_cast<__attribute__((address_space(3))) unsigned*>(lofs);
    auto gp = (const __attribute__((address_space(1))) unsigned*)g;
    __builtin_amdgcn_global_load_lds(gp, lp, 16, 0, 0);
}

// ---- fused convert + stats partials --------------------------------------
// 512 blocks x 196 rows: emb fp32 -> bf16 (zero-padded), esq, and per-block
// partials S = sum e_j (bf16-rounded), T = sum esq_j*e_j, E1 = sum esq,
// E2 = sum esq^2 (j < NODES only).

__global__ void convert_stats_kernel(const float* __restrict__ emb,
                                     unsigned short* __restrict__ Ebf,
                                     float* __restrict__ esq,
                                     float* __restrict__ Spart,
                                     float* __restrict__ Tpart,
                                     float* __restrict__ E1part,
                                     float* __restrict__ E2part) {
    __shared__ float Sl[4][512];
    __shared__ float Tl[4][512];
    __shared__ float ew[8];
    const int b = blockIdx.x, t = threadIdx.x;
    const int lane = t & 63, wave = t >> 6;
    const int r0 = b * 196;
    float sacc[8], tacc[8];
    #pragma unroll
    for (int k = 0; k < 8; ++k) { sacc[k] = 0.f; tacc[k] = 0.f; }
    float e1 = 0.f, e2 = 0.f;
    for (int i = 0; i < 49; ++i) {
        const int row = r0 + i * 4 + wave;
        if (row >= NPAD) continue;
        const bool real = row < NODES;
        float v[8];
        float ss = 0.f;
        if (real) {
            const float4* p = (const float4*)(emb + (size_t)row * DIM + lane * 8);
            float4 a = p[0], bb = p[1];
            v[0]=a.x; v[1]=a.y; v[2]=a.z; v[3]=a.w;
            v[4]=bb.x; v[5]=bb.y; v[6]=bb.z; v[7]=bb.w;
            #pragma unroll
            for (int k = 0; k < 8; ++k) ss += v[k] * v[k];
        } else {
            #pragma unroll
            for (int k = 0; k < 8; ++k) v[k] = 0.f;
        }
        #pragma unroll
        for (int o = 1; o < 64; o <<= 1) ss += __shfl_xor(ss, o);
        ushort8 o8;
        float vr[8];
        #pragma unroll
        for (int k = 0; k < 8; ++k) { o8[k] = f2bf(v[k]); vr[k] = bf2f(o8[k]); }
        *(ushort8*)(Ebf + (size_t)row * DIM + lane * 8) = o8;
        if (lane == 0) esq[row] = ss;
        if (real) {
            #pragma unroll
            for (int k = 0; k < 8; ++k) { sacc[k] += vr[k]; tacc[k] += ss * vr[k]; }
            if (lane == 0) { e1 += ss; e2 += ss * ss; }
        }
    }
    #pragma unroll
    for (int k = 0; k < 8; ++k) {
        Sl[wave][lane * 8 + k] = sacc[k];
        Tl[wave][lane * 8 + k] = tacc[k];
    }
    if (lane == 0) { ew[wave] = e1; ew[4 + wave] = e2; }
    __syncthreads();
    #pragma unroll
    for (int kk = 0; kk < 2; ++kk) {
        const int d = 2 * t + kk;
        Spart[(size_t)b * 512 + d] = Sl[0][d] + Sl[1][d] + Sl[2][d] + Sl[3][d];
        Tpart[(size_t)b * 512 + d] = Tl[0][d] + Tl[1][d] + Tl[2][d] + Tl[3][d];
    }
    if (t == 0) E1part[b] = ew[0] + ew[1] + ew[2] + ew[3];
    if (t == 1) E2part[b] = ew[4] + ew[5] + ew[6] + ew[7];
}

__global__ void stats_merge_kernel(const float* __restrict__ Spart,
                                   const float* __restrict__ Tpart,
                                   const float* __restrict__ E1part,
                                   const float* __restrict__ E2part,
                                   float* __restrict__ Svec,
                                   float* __restrict__ Tvec,
                                   double* __restrict__ E12) {
    const int t = threadIdx.x;   // 1024 threads
    if (t < 512) {
        float s = 0.f;
        for (int b = 0; b < 512; ++b) s += Spart[(size_t)b * 512 + t];
        Svec[t] = s;
    } else {
        const int d = t - 512;
        float s = 0.f;
        for (int b = 0; b < 512; ++b) s += Tpart[(size_t)b * 512 + d];
        Tvec[d] = s;
    }
    if (t == 0) { double a = 0.0; for (int b = 0; b < 512; ++b) a += (double)E1part[b]; E12[0] = a; }
    if (t == 1) { double a = 0.0; for (int b = 0; b < 512; ++b) a += (double)E2part[b]; E12[1] = a; }
}

// gather A rows (bf16) + c[m] = pos - |a|^2 + gamma ; posv[p] = pos
__global__ void gather_kernel(const int* __restrict__ pairs,
                              const float* __restrict__ emb,
                              unsigned short* __restrict__ Abf,
                              float* __restrict__ cvec,
                              float* __restrict__ posv) {
    const int p    = blockIdx.x;
    const int lane = threadIdx.x;
    const int li = pairs[2 * p], ri = pairs[2 * p + 1];
    const float4* pl = (const float4*)(emb + (size_t)li * DIM + lane * 8);
    const float4* pr = (const float4*)(emb + (size_t)ri * DIM + lane * 8);
    float4 a0 = pl[0], a1 = pl[1];
    float4 b0 = pr[0], b1 = pr[1];
    float la[8] = {a0.x,a0.y,a0.z,a0.w,a1.x,a1.y,a1.z,a1.w};
    float lb[8] = {b0.x,b0.y,b0.z,b0.w,b1.x,b1.y,b1.z,b1.w};
    float sa = 0.f, sb = 0.f, sd = 0.f;
    ushort8 oa, ob;
    #pragma unroll
    for (int i = 0; i < 8; ++i) {
        sa += la[i] * la[i];
        sb += lb[i] * lb[i];
        float d = la[i] - lb[i];
        sd += d * d;
        oa[i] = f2bf(la[i]);
        ob[i] = f2bf(lb[i]);
    }
    *(ushort8*)(Abf + (size_t)p * DIM + lane * 8)            = oa;
    *(ushort8*)(Abf + (size_t)(NPAIR + p) * DIM + lane * 8)  = ob;
    #pragma unroll
    for (int off = 1; off < 64; off <<= 1) {
        sa += __shfl_xor(sa, off);
        sb += __shfl_xor(sb, off);
        sd += __shfl_xor(sd, off);
    }
    if (lane == 0) {
        cvec[p]         = sd - sa + GAMMA_F;
        cvec[NPAIR + p] = sd - sb + GAMMA_F;
        posv[p]         = sd;
    }
}

// ---- Gram GEMM: Gpart[bz] = partial E^T E --------------------------------

__launch_bounds__(256, 2)
__global__ void gram_kernel(const unsigned short* __restrict__ Ebf,
                            float* __restrict__ Gpart) {
    __shared__ unsigned short ldsA[64 * 128];
    __shared__ unsigned short ldsB[64 * 128];
    const int tid  = threadIdx.x;
    const int lane = tid & 63;
    const int wave = tid >> 6;
    const int wx = wave & 1, wy = wave >> 1;
    const int d1base = blockIdx.y * 128;
    const int d2base = blockIdx.x * 128;
    const int bz = blockIdx.z;
    const int r15 = lane & 15, q = lane >> 4;

    f32x4 zero4 = {0.f, 0.f, 0.f, 0.f};
    f32x4 acc[4][4];
    #pragma unroll
    for (int i = 0; i < 4; ++i)
        #pragma unroll
        for (int j = 0; j < 4; ++j) acc[i][j] = zero4;

    for (int jc = bz; jc < NPAD / 64; jc += 32) {
        const int j0 = jc * 64;
        #pragma unroll
        for (int ii = 0; ii < 4; ++ii) {
            const int iss = wave * 4 + ii;
            const int row = iss * 4 + (lane >> 4);
            gload_lds16(Ebf + (size_t)(j0 + row) * DIM + d1base + (lane & 15) * 8,
                        &ldsA[iss * 4 * 128]);
            gload_lds16(Ebf + (size_t)(j0 + row) * DIM + d2base + (lane & 15) * 8,
                        &ldsB[iss * 4 * 128]);
        }
        __builtin_amdgcn_s_waitcnt(0);
        __syncthreads();
        #pragma unroll
        for (int h = 0; h < 2; ++h) {
            short8 af[4], bfv[4];
            #pragma unroll
            for (int mt = 0; mt < 4; ++mt) {
                const int m = wy * 64 + mt * 16 + r15;
                #pragma unroll
                for (int i = 0; i < 8; ++i)
                    af[mt][i] = (short)ldsA[(h * 32 + q * 8 + i) * 128 + m];
            }
            #pragma unroll
            for (int nt = 0; nt < 4; ++nt) {
                const int n = wx * 64 + nt * 16 + r15;
                #pragma unroll
                for (int i = 0; i < 8; ++i)
                    bfv[nt][i] = (short)ldsB[(h * 32 + q * 8 + i) * 128 + n];
            }
            #pragma unroll
            for (int mt = 0; mt < 4; ++mt)
                #pragma unroll
                for (int nt = 0; nt < 4; ++nt)
                    acc[mt][nt] = __builtin_amdgcn_mfma_f32_16x16x32_bf16(
                        af[mt], bfv[nt], acc[mt][nt], 0, 0, 0);
        }
        __syncthreads();
    }
    float* gp = Gpart + (size_t)bz * 512 * 512;
    #pragma unroll
    for (int mt = 0; mt < 4; ++mt)
        #pragma unroll
        for (int r = 0; r < 4; ++r) {
            const int d1 = d1base + wy * 64 + mt * 16 + q * 4 + r;
            #pragma unroll
            for (int nt = 0; nt < 4; ++nt) {
                const int d2 = d2base + wx * 64 + nt * 16 + r15;
                gp[d1 * 512 + d2] = acc[mt][nt][r];
            }
        }
}

__global__ void gram_merge_kernel(const float* __restrict__ Gpart,
                                  float* __restrict__ G) {
    const int idx = blockIdx.x * 256 + threadIdx.x;   // 1024 blocks
    float s = 0.f;
    for (int b = 0; b < 32; ++b) s += Gpart[(size_t)b * 512 * 512 + idx];
    G[idx] = s;
}

// ---- per-row closed-form stats -> alpha, shift ---------------------------
// shift C = alpha*mu + SHIFT ; loss = TAU + SHIFT + log(sum exp(alpha*x - C))

__launch_bounds__(256)
__global__ void gu_kernel(const unsigned short* __restrict__ Abf,
                          const float* __restrict__ G,
                          const float* __restrict__ Svec,
                          const float* __restrict__ Tvec,
                          const double* __restrict__ E12,
                          const float* __restrict__ cvec,
                          const float* __restrict__ posv,
                          const int* __restrict__ pairs,
                          float* __restrict__ alpha_v,
                          float* __restrict__ shift_v) {
    __shared__ float u[8][512];
    __shared__ float red[8][3][4];
    const int t = threadIdx.x;
    const int lane = t & 63, wave = t >> 6;
    const int r0 = blockIdx.x * 8;
    #pragma unroll
    for (int p = 0; p < 8; ++p) {
        unsigned pk = *(const unsigned*)(Abf + (size_t)(r0 + p) * DIM + 2 * t);
        u[p][2 * t]     = bf2f((unsigned short)(pk & 0xffffu));
        u[p][2 * t + 1] = bf2f((unsigned short)(pk >> 16));
    }
    __syncthreads();
    float acc0[8], acc1[8];
    #pragma unroll
    for (int p = 0; p < 8; ++p) { acc0[p] = 0.f; acc1[p] = 0.f; }
    for (int d1 = 0; d1 < 512; ++d1) {
        const float2 g = *(const float2*)(G + d1 * 512 + 2 * t);
        #pragma unroll
        for (int p = 0; p < 8; ++p) {
            const float up = u[p][d1];
            acc0[p] += up * g.x;
            acc1[p] += up * g.y;
        }
    }
    const float sv0 = Svec[2 * t], sv1 = Svec[2 * t + 1];
    const float tv0 = Tvec[2 * t], tv1 = Tvec[2 * t + 1];
    #pragma unroll
    for (int p = 0; p < 8; ++p) {
        const float u0 = u[p][2 * t], u1 = u[p][2 * t + 1];
        float pdS = u0 * sv0 + u1 * sv1;
        float pdT = u0 * tv0 + u1 * tv1;
        float pq  = u0 * acc0[p] + u1 * acc1[p];
        #pragma unroll
        for (int off = 1; off < 64; off <<= 1) {
            pdS += __shfl_xor(pdS, off);
            pdT += __shfl_xor(pdT, off);
            pq  += __shfl_xor(pq,  off);
        }
        if (lane == 0) {
            red[p][0][wave] = pdS;
            red[p][1][wave] = pdT;
            red[p][2][wave] = pq;
        }
    }
    __syncthreads();
    if (t < 8) {
        const int p = t;
        const double dS = (double)red[p][0][0] + red[p][0][1] + red[p][0][2] + red[p][0][3];
        const double dT = (double)red[p][1][0] + red[p][1][1] + red[p][1][2] + red[p][1][3];
        const double qq = (double)red[p][2][0] + red[p][2][1] + red[p][2][2] + red[p][2][3];
        const int row = r0 + p;
        const int pp  = row & (NPAIR - 1);
        const double c  = (double)cvec[row];
        const double E1 = E12[0], E2 = E12[1];
        const double N  = (double)NODES;
        double Sx  = N * c + 2.0 * dS - E1;
        double Sxx = (N * c * c - 2.0 * c * E1 + E2) + 4.0 * (c * dS - dT) + 4.0 * qq;
        const int li = pairs[2 * pp], ri = pairs[2 * pp + 1];
        const double pos = (double)posv[pp];
        if (li != ri) {
            const double x1 = pos + (double)GAMMA_F, x2 = (double)GAMMA_F;
            Sx  -= x1 + x2;
            Sxx -= x1 * x1 + x2 * x2;
        } else {
            Sx -= 2.0 * (double)GAMMA_F;   // value flips sign; square unchanged
        }
        const double mu  = Sx / N;
        const double var = Sxx / N - mu * mu;
        const double sd  = sqrt(fmax(var, 1e-30));
        const double al  = (double)LAMB_F / sd;
        alpha_v[row] = (float)al;
        shift_v[row] = (float)(al * mu + (double)SHIFT_F);
    }
}

// ---- the big GEMM (single pass) + shifted-exp partial epilogue -----------

__launch_bounds__(256, 2)
__global__ void gemm_kernel(const unsigned short* __restrict__ Abf,
                            const unsigned short* __restrict__ Ebf,
                            const float* __restrict__ cvec,
                            const float* __restrict__ esq,
                            const int*   __restrict__ pairs,
                            const float* __restrict__ alpha_v,
                            const float* __restrict__ shift_v,
                            float* __restrict__ psum) {
    __shared__ unsigned short ldsA[TM * BK];  // 16 KB
    __shared__ unsigned short ldsB[TN * BK];  // 16 KB
    __shared__ float red_s[2][TM];
    __shared__ float alsh[TM], csh[TM], cmsh[TM];
    __shared__ int   lish[TM], rish[TM];

    const int tid  = threadIdx.x;
    const int lane = tid & 63;
    const int wave = tid >> 6;
    const int wx = wave & 1;
    const int wy = wave >> 1;
    const int nb = blockIdx.x;
    const int n0 = nb * TN;
    const int m0 = blockIdx.y * TM;

    if (tid < TM) {
        const int gm = m0 + tid;
        alsh[tid] = alpha_v[gm];
        csh[tid]  = shift_v[gm];
        cmsh[tid] = cvec[gm];
        const int p = gm & (NPAIR - 1);
        lish[tid] = pairs[2 * p];
        rish[tid] = pairs[2 * p + 1];
    }

    f32x4 zero4 = {0.f, 0.f, 0.f, 0.f};
    f32x4 acc[4][4];
    #pragma unroll
    for (int i = 0; i < 4; ++i)
        #pragma unroll
        for (int j = 0; j < 4; ++j) acc[i][j] = zero4;

    const int lrow   = lane >> 3;
    const int lchunk = lane & 7;
    const int r15 = lane & 15;
    const int q   = lane >> 4;

    for (int kt = 0; kt < DIM / BK; ++kt) {
        const int kb = kt * BK;
        #pragma unroll
        for (int j = 0; j < 4; ++j) {
            const int rbase = (wave * 4 + j) * 8;
            const int row   = rbase + lrow;
            const int gch   = lchunk ^ (row & 7);
            gload_lds16(Abf + ((size_t)(m0 + row) * DIM + kb + gch * 8), &ldsA[rbase * BK]);
            gload_lds16(Ebf + ((size_t)(n0 + row) * DIM + kb + gch * 8), &ldsB[rbase * BK]);
        }
        __builtin_amdgcn_s_waitcnt(0);
        __syncthreads();
        #pragma unroll
        for (int h = 0; h < 2; ++h) {
            short8 af[4], bfr[4];
            #pragma unroll
            for (int mt = 0; mt < 4; ++mt) {
                int row = wy * 64 + mt * 16 + r15;
                int c   = (h * 4 + q) ^ (row & 7);
                af[mt] = *(const short8*)&ldsA[row * BK + c * 8];
            }
            #pragma unroll
            for (int nt = 0; nt < 4; ++nt) {
                int row = wx * 64 + nt * 16 + r15;
                int c   = (h * 4 + q) ^ (row & 7);
                bfr[nt] = *(const short8*)&ldsB[row * BK + c * 8];
            }
            #pragma unroll
            for (int mt = 0; mt < 4; ++mt)
                #pragma unroll
                for (int nt = 0; nt < 4; ++nt)
                    acc[mt][nt] = __builtin_amdgcn_mfma_f32_16x16x32_bf16(
                        af[mt], bfr[nt], acc[mt][nt], 0, 0, 0);
        }
        __syncthreads();
    }

    // epilogue: se = sum exp(al*x - C); C absorbs mu and 7-sigma headroom
    #pragma unroll
    for (int mt = 0; mt < 4; ++mt) {
        #pragma unroll
        for (int r = 0; r < 4; ++r) {
            const int rit = wy * 64 + mt * 16 + q * 4 + r;
            const float cm = cmsh[rit];
            const float al = alsh[rit];
            const float Cc = csh[rit];
            const int li = lish[rit], ri = rish[rit];
            float se = 0.f;
            #pragma unroll
            for (int nt = 0; nt < 4; ++nt) {
                const int gn = n0 + wx * 64 + nt * 16 + r15;
                float xv = cm + 2.0f * acc[mt][nt][r] - esq[gn];
                float msk = 1.0f - (float)(gn == li) - (float)(gn == ri);
                xv *= msk;
                float term = __expf(fmaf(al, xv, -Cc));
                se += (gn < NODES) ? term : 0.f;
            }
            #pragma unroll
            for (int o = 1; o < 16; o <<= 1) se += __shfl_xor(se, o);
            if (r15 == 0) red_s[wx][rit] = se;
        }
    }
    __syncthreads();
    if (tid < TM) {
        psum[(size_t)nb * MROWS + m0 + tid] = red_s[0][tid] + red_s[1][tid];
    }
}

// ---- partial-sum tree over nb, then loss, then mean ----------------------

__global__ void lse_part_kernel(const float* __restrict__ psum,
                                float* __restrict__ lsep) {
    const int row = blockIdx.x * 256 + threadIdx.x;   // 16 x 256 = 4096
    const int c   = blockIdx.y;                       // 4 chunks
    const int nb0 = c * 196;
    const int nb1 = (nb0 + 196 < NB) ? nb0 + 196 : NB;
    float s = 0.f;
    for (int nb = nb0; nb < nb1; ++nb)
        s += psum[(size_t)nb * MROWS + row];
    lsep[(size_t)c * MROWS + row] = s;
}

__global__ void loss_kernel(const float* __restrict__ lsep,
                            float* __restrict__ loss_v) {
    const int row = blockIdx.x * 256 + threadIdx.x;   // 16 blocks
    const float s = lsep[row] + lsep[MROWS + row]
                  + lsep[2 * MROWS + row] + lsep[3 * MROWS + row];
    loss_v[row] = (TAU_F + SHIFT_F) + logf(s);
}

__global__ void final_kernel(const float* __restrict__ loss_v,
                             float* __restrict__ out) {
    __shared__ double wpart[4];
    int t = threadIdx.x;
    double s = 0.0;
    for (int i = t; i < MROWS; i += 256)
        s += (double)loss_v[i];
    #pragma unroll
    for (int off = 1; off < 64; off <<= 1) s += __shfl_xor(s, off);
    if ((t & 63) == 0) wpart[t >> 6] = s;
    __syncthreads();
    if (t == 0) out[0] = (float)((wpart[0] + wpart[1] + wpart[2] + wpart[3]) / (double)NPAIR);
}

// ---- host ----------------------------------------------------------------

extern "C" void kernel_launch(void* const* d_in, const int* in_sizes, int n_in,
                              void* d_out, int out_size, void* d_ws, size_t ws_size,
                              hipStream_t stream) {
    const int*   pairs = (const int*)d_in[0];
    const float* emb   = (const float*)d_in[1];
    float* out = (float*)d_out;

    char* ws = (char*)d_ws;
    size_t off = 0;
    auto alloc = [&](size_t bytes) -> void* {
        void* p = ws + off;
        off += (bytes + 255) & ~(size_t)255;
        return p;
    };
    unsigned short* Ebf = (unsigned short*)alloc((size_t)NPAD * DIM * 2);
    unsigned short* Abf = (unsigned short*)alloc((size_t)MROWS * DIM * 2);
    float*  esq     = (float*)alloc((size_t)NPAD * 4);
    float*  cvec    = (float*)alloc((size_t)MROWS * 4);
    float*  posv    = (float*)alloc((size_t)NPAIR * 4);
    float*  Spart   = (float*)alloc((size_t)512 * DIM * 4);
    float*  Tpart   = (float*)alloc((size_t)512 * DIM * 4);
    float*  E1part  = (float*)alloc((size_t)512 * 4);
    float*  E2part  = (float*)alloc((size_t)512 * 4);
    float*  Svec    = (float*)alloc((size_t)DIM * 4);
    float*  Tvec    = (float*)alloc((size_t)DIM * 4);
    double* E12     = (double*)alloc(2 * sizeof(double));
    float*  G       = (float*)alloc((size_t)512 * 512 * 4);
    float*  alpha_v = (float*)alloc((size_t)MROWS * 4);
    float*  shift_v = (float*)alloc((size_t)MROWS * 4);
    float*  lsep    = (float*)alloc((size_t)4 * MROWS * 4);
    float*  loss_v  = (float*)alloc((size_t)MROWS * 4);
    // union region: Gram partials (32 MB), then psum (12.8 MB) after gram_merge
    char* uni = (char*)alloc((size_t)32 * 512 * 512 * 4);
    float* Gpart = (float*)uni;
    float* psum  = (float*)uni;
    if (off > ws_size) return;  // workspace too small — fail visibly

    convert_stats_kernel<<<512, 256, 0, stream>>>(emb, Ebf, esq,
                                                  Spart, Tpart, E1part, E2part);
    stats_merge_kernel<<<1, 1024, 0, stream>>>(Spart, Tpart, E1part, E2part,
                                               Svec, Tvec, E12);
    gather_kernel<<<NPAIR, 64, 0, stream>>>(pairs, emb, Abf, cvec, posv);

    gram_kernel<<<dim3(4, 4, 32), 256, 0, stream>>>(Ebf, Gpart);
    gram_merge_kernel<<<1024, 256, 0, stream>>>(Gpart, G);
    gu_kernel<<<MROWS / 8, 256, 0, stream>>>(Abf, G, Svec, Tvec, E12,
                                             cvec, posv, pairs, alpha_v, shift_v);

    gemm_kernel<<<dim3(NB, MPAGES), 256, 0, stream>>>(Abf, Ebf, cvec, esq, pairs,
                                                      alpha_v, shift_v, psum);
    lse_part_kernel<<<dim3(16, 4), 256, 0, stream>>>(psum, lsep);
    loss_kernel<<<16, 256, 0, stream>>>(lsep, loss_v);
    final_kernel<<<1, 256, 0, stream>>>(loss_v, out);
}